// Round 13
// baseline (424.705 us; speedup 1.0000x reference)
//
#include <hip/hip_runtime.h>

typedef __attribute__((ext_vector_type(4))) float f32x4;
typedef __attribute__((ext_vector_type(8))) __bf16 bf16x8;
typedef unsigned int u32;

constexpr int FD = 128;   // feature dim D = H = 128

__device__ __forceinline__ u32 pk2(float a, float b) {
  union { __bf16 h[2]; u32 u; } cv; cv.h[0] = (__bf16)a; cv.h[1] = (__bf16)b; return cv.u;
}
__device__ __forceinline__ bf16x8 mk8(u32 a, u32 b, u32 c, u32 d) {
  union { u32 w[4]; bf16x8 v; } cv; cv.w[0] = a; cv.w[1] = b; cv.w[2] = c; cv.w[3] = d; return cv.v;
}
__device__ __forceinline__ bf16x8 pack8f(const f32x4 a, const f32x4 b) {
  return mk8(pk2(a[0], a[1]), pk2(a[2], a[3]), pk2(b[0], b[1]), pk2(b[2], b[3]));
}
__device__ __forceinline__ uint4 pack8(const float* v) {
  union { __bf16 h[8]; uint4 u; } cv;
#pragma unroll
  for (int q = 0; q < 8; ++q) cv.h[q] = (__bf16)v[q];
  return cv.u;
}
__device__ __forceinline__ unsigned int pack2(float a, float b) { return pk2(a, b); }

// node_x f32 -> bf16 table (halves random-gather bytes in the edge kernel)
__global__ void cvt_bf16(const float* __restrict__ x, unsigned short* __restrict__ o, int n8) {
  int i = blockIdx.x * 256 + threadIdx.x;
  if (i >= n8) return;
  const float* p = x + (size_t)i * 8;
  float v[8];
#pragma unroll
  for (int q = 0; q < 8; ++q) v[q] = p[q];
  *(uint4*)(o + (size_t)i * 8) = pack8(v);
}

// Pack a (K,128) f32 weight matrix into MFMA fragment order, bf16.
// The formula is symmetric: the same buffer serves as B-frags (col=lane&15)
// for the node kernel AND as A-frags of W^T (row=lane&15) for the edge kernel.
__global__ void pack_weights(const float* __restrict__ mw0, const float* __restrict__ mw1,
                             const float* __restrict__ mw2, const float* __restrict__ uw0,
                             const float* __restrict__ uw1, const float* __restrict__ uw2,
                             unsigned short* __restrict__ wp) {
  int tid = blockIdx.x * 256 + threadIdx.x;   // 576*256 == 147456 exactly
  const float* src; int base, K;
  if      (tid < 49152)  { src = mw0; base = 0;      K = 384; }
  else if (tid < 65536)  { src = mw1; base = 49152;  K = 128; }
  else if (tid < 81920)  { src = mw2; base = 65536;  K = 128; }
  else if (tid < 114688) { src = uw0; base = 81920;  K = 256; }
  else if (tid < 131072) { src = uw1; base = 114688; K = 128; }
  else                   { src = uw2; base = 131072; K = 128; }
  int i = tid - base;
  int k = i >> 7, n = i & 127;
  int KS = K >> 5;
  int dst = base + (((n >> 4) * KS + (k >> 5)) * 64 + ((k >> 3) & 3) * 16 + (n & 15)) * 8 + (k & 7);
  union { __bf16 h; unsigned short s; } cv; cv.h = (__bf16)src[i];
  wp[dst] = cv.s;
}

// Edge kernel, transposed dataflow: 128 edges/block, 256 threads = 4 waves,
// each wave independently computes msg^T for its 32 edges. C^T = W^T @ x^T:
// A-operand = W^T frags (L2-resident packed buffer), B-operand = activation^T
// frags loaded DIRECTLY from global (gather == fragment pattern). Layer-to-layer
// transpose in-register via shfl. ZERO block barriers after the 2.5KB param load.
__global__ __launch_bounds__(256, 4)
void in_edge_kernel(const float* __restrict__ node_x, const unsigned short* __restrict__ nxbf,
                    const float* __restrict__ edge_attr,
                    const int* __restrict__ eidx, const unsigned short* __restrict__ wp,
                    const float* __restrict__ b0p, const float* __restrict__ b1p,
                    const float* __restrict__ b2p, const float* __restrict__ gp,
                    const float* __restrict__ bep,
                    unsigned short* __restrict__ msg, int* __restrict__ head,
                    int* __restrict__ nxt, float* __restrict__ agg,
                    int use_sort, int E) {
  __shared__ float sP[5][128];   // b0, b1, b2, g, beta

  const int t = threadIdx.x;
  const int lane = t & 63, w = t >> 6;
  const int ln = lane & 15, g16 = lane >> 4;
  const int e0w = blockIdx.x * 128 + w * 32;
  const int erow0 = e0w + ln, erow1 = e0w + 16 + ln;
  const int kg = 8 * g16;

  int si0 = 0, si1 = 0, di0 = 0, di1 = 0;
  if (erow0 < E) { si0 = eidx[erow0]; di0 = eidx[E + erow0]; }
  if (erow1 < E) { si1 = eidx[erow1]; di1 = eidx[E + erow1]; }

  if (t < 128) {
    sP[0][t] = b0p[t]; sP[1][t] = b1p[t]; sP[2][t] = b2p[t];
    sP[3][t] = gp[t];  sP[4][t] = bep[t];
  }
  if (use_sort && lane < 32) {
    int e = e0w + lane;
    if (e < E) { int d = (lane < 16) ? di0 : di1; nxt[e] = atomicExch(&head[d], e); }
  }
  __syncthreads();   // the only block barrier

  auto xf = [&](int idx, int ko) -> bf16x8 {     // ko in shorts
    if (nxbf) return *(const bf16x8*)(nxbf + (size_t)idx * FD + ko);
    f32x4 a = *(const f32x4*)(node_x + (size_t)idx * FD + ko);
    f32x4 b = *(const f32x4*)(node_x + (size_t)idx * FD + ko + 4);
    return pack8f(a, b);
  };
  auto eaf = [&](int row, int ko) -> bf16x8 {
    f32x4 a = {0.f,0.f,0.f,0.f}, b = {0.f,0.f,0.f,0.f};
    if (row < E) {
      a = *(const f32x4*)(edge_attr + (size_t)row * FD + ko);
      b = *(const f32x4*)(edge_attr + (size_t)row * FD + ko + 4);
    }
    return pack8f(a, b);
  };

  // B-gather ring, 3-deep prefetch (concat: kb 0-3 x_dst, 4-7 x_src, 8-11 ea)
  bf16x8 rb[4][2];
  auto loadkb = [&](int kb) {
    int s = kb & 3;
    if (kb < 4)      { int ko = kb * 32 + kg;       rb[s][0] = xf(di0, ko);     rb[s][1] = xf(di1, ko); }
    else if (kb < 8) { int ko = (kb - 4) * 32 + kg; rb[s][0] = xf(si0, ko);     rb[s][1] = xf(si1, ko); }
    else             { int ko = (kb - 8) * 32 + kg; rb[s][0] = eaf(erow0, ko);  rb[s][1] = eaf(erow1, ko); }
  };

  f32x4 acc[8][2];
#pragma unroll
  for (int mb = 0; mb < 8; ++mb)
#pragma unroll
    for (int nb = 0; nb < 2; ++nb) acc[mb][nb] = (f32x4){0.f, 0.f, 0.f, 0.f};

  loadkb(0); loadkb(1); loadkb(2);

  // ---- layer 0: K=384 ----
#pragma unroll
  for (int kb = 0; kb < 12; ++kb) {
    if (kb + 3 < 12) loadkb(kb + 3);
    const int s = kb & 3;
#pragma unroll
    for (int mb = 0; mb < 8; ++mb) {
      bf16x8 a = *(const bf16x8*)(wp + (size_t)((mb * 12 + kb) * 64 + lane) * 8);
      acc[mb][0] = __builtin_amdgcn_mfma_f32_16x16x32_bf16(a, rb[s][0], acc[mb][0], 0, 0, 0);
      acc[mb][1] = __builtin_amdgcn_mfma_f32_16x16x32_bf16(a, rb[s][1], acc[mb][1], 0, 0, 0);
    }
  }

  // In-register transpose: D-frags (C^T) -> next-layer B-frags, with bias+relu.
  const int s0l = ln + ((g16 & 1) << 5);
  const int s1l = s0l + 16;
  const bool hi = g16 >= 2;
  bf16x8 Bn[4][2];

  auto transition = [&](int lyr) {
    u32 clo[8][2], chi[8][2];
#pragma unroll
    for (int mb = 0; mb < 8; ++mb) {
      f32x4 bv = *(const f32x4*)&sP[lyr][mb * 16 + 4 * g16];
#pragma unroll
      for (int nb = 0; nb < 2; ++nb) {
        float v0 = fmaxf(acc[mb][nb][0] + bv[0], 0.f);
        float v1 = fmaxf(acc[mb][nb][1] + bv[1], 0.f);
        float v2 = fmaxf(acc[mb][nb][2] + bv[2], 0.f);
        float v3 = fmaxf(acc[mb][nb][3] + bv[3], 0.f);
        clo[mb][nb] = pk2(v0, v1); chi[mb][nb] = pk2(v2, v3);
      }
    }
#pragma unroll
    for (int kb = 0; kb < 4; ++kb)
#pragma unroll
      for (int nb = 0; nb < 2; ++nb) {
        u32 a0 = __shfl((int)clo[2 * kb][nb], s0l, 64),     a1 = __shfl((int)chi[2 * kb][nb], s0l, 64);
        u32 a2 = __shfl((int)clo[2 * kb][nb], s1l, 64),     a3 = __shfl((int)chi[2 * kb][nb], s1l, 64);
        u32 b0 = __shfl((int)clo[2 * kb + 1][nb], s0l, 64), b1 = __shfl((int)chi[2 * kb + 1][nb], s0l, 64);
        u32 b2 = __shfl((int)clo[2 * kb + 1][nb], s1l, 64), b3 = __shfl((int)chi[2 * kb + 1][nb], s1l, 64);
        Bn[kb][nb] = mk8(hi ? b0 : a0, hi ? b1 : a1, hi ? b2 : a2, hi ? b3 : a3);
      }
#pragma unroll
    for (int mb = 0; mb < 8; ++mb)
#pragma unroll
      for (int nb = 0; nb < 2; ++nb) acc[mb][nb] = (f32x4){0.f, 0.f, 0.f, 0.f};
  };

  transition(0);

  // ---- layer 1: K=128 ----
#pragma unroll
  for (int kb = 0; kb < 4; ++kb)
#pragma unroll
    for (int mb = 0; mb < 8; ++mb) {
      bf16x8 a = *(const bf16x8*)(wp + 49152 + (size_t)((mb * 4 + kb) * 64 + lane) * 8);
      acc[mb][0] = __builtin_amdgcn_mfma_f32_16x16x32_bf16(a, Bn[kb][0], acc[mb][0], 0, 0, 0);
      acc[mb][1] = __builtin_amdgcn_mfma_f32_16x16x32_bf16(a, Bn[kb][1], acc[mb][1], 0, 0, 0);
    }

  transition(1);

  // ---- layer 2: K=128 ----
#pragma unroll
  for (int kb = 0; kb < 4; ++kb)
#pragma unroll
    for (int mb = 0; mb < 8; ++mb) {
      bf16x8 a = *(const bf16x8*)(wp + 65536 + (size_t)((mb * 4 + kb) * 64 + lane) * 8);
      acc[mb][0] = __builtin_amdgcn_mfma_f32_16x16x32_bf16(a, Bn[kb][0], acc[mb][0], 0, 0, 0);
      acc[mb][1] = __builtin_amdgcn_mfma_f32_16x16x32_bf16(a, Bn[kb][1], acc[mb][1], 0, 0, 0);
    }

  // ---- LayerNorm: add b2, reduce over cols (g16 lanes) via 2 shfl_xor ----
  float mean[2], rstd[2];
#pragma unroll
  for (int nb = 0; nb < 2; ++nb) {
    float p = 0.f, q = 0.f;
#pragma unroll
    for (int mb = 0; mb < 8; ++mb) {
      f32x4 bv = *(const f32x4*)&sP[2][mb * 16 + 4 * g16];
#pragma unroll
      for (int r = 0; r < 4; ++r) {
        float v = acc[mb][nb][r] + bv[r];
        acc[mb][nb][r] = v;
        p += v; q += v * v;
      }
    }
    p += __shfl_xor(p, 16, 64); p += __shfl_xor(p, 32, 64);
    q += __shfl_xor(q, 16, 64); q += __shfl_xor(q, 32, 64);
    float m_ = p * (1.f / 128.f);
    float var = q * (1.f / 128.f) - m_ * m_;
    mean[nb] = m_;
    rstd[nb] = rsqrtf(fmaxf(var, 0.f) + 1e-5f);
  }

  // ---- epilogue: scale/shift + edge_attr + store msg (or atomic fallback) ----
#pragma unroll
  for (int mb = 0; mb < 8; ++mb) {
    f32x4 gv  = *(const f32x4*)&sP[3][mb * 16 + 4 * g16];
    f32x4 bev = *(const f32x4*)&sP[4][mb * 16 + 4 * g16];
#pragma unroll
    for (int nb = 0; nb < 2; ++nb) {
      int row = nb ? erow1 : erow0;
      if (row < E) {
        f32x4 ea = *(const f32x4*)(edge_attr + (size_t)row * FD + mb * 16 + 4 * g16);
        float v0 = (acc[mb][nb][0] - mean[nb]) * rstd[nb] * gv[0] + bev[0] + ea[0];
        float v1 = (acc[mb][nb][1] - mean[nb]) * rstd[nb] * gv[1] + bev[1] + ea[1];
        float v2 = (acc[mb][nb][2] - mean[nb]) * rstd[nb] * gv[2] + bev[2] + ea[2];
        float v3 = (acc[mb][nb][3] - mean[nb]) * rstd[nb] * gv[3] + bev[3] + ea[3];
        if (use_sort) {
          uint2 o; o.x = pk2(v0, v1); o.y = pk2(v2, v3);
          *(uint2*)(msg + (size_t)row * FD + mb * 16 + 4 * g16) = o;
        } else {
          int d = nb ? di1 : di0;
          float* ap = agg + (size_t)d * FD + mb * 16 + 4 * g16;
          atomicAdd(ap + 0, v0); atomicAdd(ap + 1, v1);
          atomicAdd(ap + 2, v2); atomicAdd(ap + 3, v3);
        }
      }
    }
  }
}

// Node kernel: 64 nodes/block (R7 verbatim, frag-order LDS).
__global__ __launch_bounds__(512, 8)
void in_node_kernel(const float* __restrict__ node_x, const unsigned short* __restrict__ nxbf,
                    const unsigned short* __restrict__ msg, const int* __restrict__ head,
                    const int* __restrict__ nxt, const float* __restrict__ agg,
                    const unsigned short* __restrict__ wp,
                    const float* __restrict__ b0p, const float* __restrict__ b1p,
                    const float* __restrict__ b2p, const float* __restrict__ gp,
                    const float* __restrict__ bep, float* __restrict__ out,
                    int use_sort, int N) {
  __shared__ unsigned short sBuf[2048 * 8];
  __shared__ float sG[128], sB[128];

  const int t = threadIdx.x;
  const int r0 = blockIdx.x * 64;
  const int lane = t & 63, w = t >> 6;
  const int ln = lane & 15, g16 = lane >> 4;
  const int col = w * 16 + ln;
  const int rdoff = ln * 32 + g16 * 8;
  const int stoff = (w >> 1) * 2048 + g16 * 128
                  + (((2 * w) + (ln >> 3)) & 3) * 8 + (ln & 7);

  bf16x8 b0[4];
#pragma unroll
  for (int ks = 0; ks < 4; ++ks)
    b0[ks] = *(const bf16x8*)(wp + 81920 + (size_t)((w * 8 + ks) * 64 + lane) * 8);

  if (t < 128)      sG[t] = gp[t];
  else if (t < 256) sB[t - 128] = bep[t - 128];

  if (nxbf) {
#pragma unroll
    for (int it = 0; it < 2; ++it) {
      int f = t + it * 512;
      int row = f >> 4, j = f & 15;
      int r = r0 + row;
      uint4 v = {0, 0, 0, 0};
      if (r < N) v = *(const uint4*)(nxbf + (size_t)r * FD + j * 8);
      int c = (((j >> 2) * 4 + (row >> 4)) * 64 + (row & 15) * 4 + (j & 3)) * 8;
      *(uint4*)&sBuf[c] = v;
    }
  } else {
#pragma unroll
    for (int it = 0; it < 8; ++it) {
      int row = (it << 3) + w;
      int r = r0 + row;
      float2 v = {0.f, 0.f};
      if (r < N) v = *(const float2*)(node_x + (size_t)r * FD + lane * 2);
      int c = (((lane >> 4) * 4 + (row >> 4)) * 64
               + (row & 15) * 4 + ((lane >> 2) & 3)) * 8 + (lane & 3) * 2;
      *(unsigned int*)&sBuf[c] = pack2(v.x, v.y);
    }
  }

  {
    int row = t >> 3, j = t & 7;
    int node = r0 + row;
    float a[16];
#pragma unroll
    for (int q = 0; q < 16; ++q) a[q] = 0.f;
    if (node < N) {
      if (use_sort) {
        int e = head[node];
        while (e >= 0) {
          int ne = nxt[e];
          bf16x8 m0 = *(const bf16x8*)(msg + (size_t)e * FD + j * 16);
          bf16x8 m1 = *(const bf16x8*)(msg + (size_t)e * FD + j * 16 + 8);
#pragma unroll
          for (int q = 0; q < 8; ++q) { a[q] += (float)m0[q]; a[8 + q] += (float)m1[q]; }
          e = ne;
        }
      } else {
        const float* ap = agg + (size_t)node * FD + j * 16;
#pragma unroll
        for (int q4 = 0; q4 < 4; ++q4) {
          f32x4 u = *(const f32x4*)(ap + q4 * 4);
#pragma unroll
          for (int q = 0; q < 4; ++q) a[q4 * 4 + q] = u[q];
        }
      }
    }
    int c = 8192 + (((j >> 1) * 4 + (row >> 4)) * 64 + (row & 15) * 4 + 2 * (j & 1)) * 8;
    float* ap2 = a;
    *(uint4*)&sBuf[c] = pack8(ap2);
    *(uint4*)&sBuf[c + 8] = pack8(ap2 + 8);
  }
  __syncthreads();

  const float b0v = b0p[col], b1v = b1p[col], b2v = b2p[col];

  f32x4 acc[4];
#pragma unroll
  for (int m = 0; m < 4; ++m) acc[m] = (f32x4){0.f, 0.f, 0.f, 0.f};

#pragma unroll
  for (int ks = 0; ks < 8; ++ks) {
    bf16x8 bb = b0[ks % 4];
    if (ks + 4 < 8)
      b0[ks % 4] = *(const bf16x8*)(wp + 81920 + (size_t)((w * 8 + ks + 4) * 64 + lane) * 8);
#pragma unroll
    for (int m = 0; m < 4; ++m) {
      bf16x8 a = *(const bf16x8*)&sBuf[(ks * 4 + m) * 512 + rdoff];
      acc[m] = __builtin_amdgcn_mfma_f32_16x16x32_bf16(a, bb, acc[m], 0, 0, 0);
    }
  }
  bf16x8 B1r[4];
#pragma unroll
  for (int ks = 0; ks < 4; ++ks)
    B1r[ks] = *(const bf16x8*)(wp + 114688 + (size_t)((w * 4 + ks) * 64 + lane) * 8);

  __syncthreads();
#pragma unroll
  for (int m = 0; m < 4; ++m)
#pragma unroll
    for (int ri = 0; ri < 4; ++ri) {
      union { __bf16 h; unsigned short s; } cv;
      cv.h = (__bf16)fmaxf(acc[m][ri] + b0v, 0.f);
      sBuf[stoff + m * 512 + ri * 32] = cv.s;
      acc[m][ri] = 0.f;
    }
  __syncthreads();

#pragma unroll
  for (int ks = 0; ks < 4; ++ks)
#pragma unroll
    for (int m = 0; m < 4; ++m) {
      bf16x8 a = *(const bf16x8*)&sBuf[(ks * 4 + m) * 512 + rdoff];
      acc[m] = __builtin_amdgcn_mfma_f32_16x16x32_bf16(a, B1r[ks], acc[m], 0, 0, 0);
    }
  bf16x8 B2r[4];
#pragma unroll
  for (int ks = 0; ks < 4; ++ks)
    B2r[ks] = *(const bf16x8*)(wp + 131072 + (size_t)((w * 4 + ks) * 64 + lane) * 8);
#pragma unroll
  for (int m = 0; m < 4; ++m)
#pragma unroll
    for (int ri = 0; ri < 4; ++ri) {
      union { __bf16 h; unsigned short s; } cv;
      cv.h = (__bf16)fmaxf(acc[m][ri] + b1v, 0.f);
      sBuf[8192 + stoff + m * 512 + ri * 32] = cv.s;
      acc[m][ri] = 0.f;
    }
  __syncthreads();

#pragma unroll
  for (int ks = 0; ks < 4; ++ks)
#pragma unroll
    for (int m = 0; m < 4; ++m) {
      bf16x8 a = *(const bf16x8*)&sBuf[8192 + (ks * 4 + m) * 512 + rdoff];
      acc[m] = __builtin_amdgcn_mfma_f32_16x16x32_bf16(a, B2r[ks], acc[m], 0, 0, 0);
    }
#pragma unroll
  for (int m = 0; m < 4; ++m)
#pragma unroll
    for (int ri = 0; ri < 4; ++ri) {
      union { __bf16 h; unsigned short s; } cv;
      cv.h = (__bf16)(acc[m][ri] + b2v);
      sBuf[stoff + m * 512 + ri * 32] = cv.s;
    }
  __syncthreads();

  {
    int row = t >> 3, j = t & 7;
    int a0 = (((j >> 1) * 4 + (row >> 4)) * 64 + (row & 15) * 4 + 2 * (j & 1)) * 8;
    bf16x8 v0 = *(const bf16x8*)&sBuf[a0];
    bf16x8 v1 = *(const bf16x8*)&sBuf[a0 + 8];
    float s1 = 0.f, s2 = 0.f;
#pragma unroll
    for (int q = 0; q < 8; ++q) {
      float a = (float)v0[q], b = (float)v1[q];
      s1 += a + b; s2 += a * a + b * b;
    }
#pragma unroll
    for (int m = 1; m < 8; m <<= 1) {
      s1 += __shfl_xor(s1, m, 64);
      s2 += __shfl_xor(s2, m, 64);
    }
    float mean = s1 * (1.f / 128.f);
    float var  = s2 * (1.f / 128.f) - mean * mean;
    float rstd = rsqrtf(fmaxf(var, 0.f) + 1e-5f);

    int node = r0 + row;
    if (node < N) {
      float o[16];
#pragma unroll
      for (int q = 0; q < 8; ++q) {
        o[q]     = ((float)v0[q] - mean) * rstd * sG[j * 16 + q]     + sB[j * 16 + q];
        o[8 + q] = ((float)v1[q] - mean) * rstd * sG[j * 16 + 8 + q] + sB[j * 16 + 8 + q];
      }
      const float* xr = node_x + (size_t)node * FD + j * 16;
      float* orow = out + (size_t)node * FD + j * 16;
#pragma unroll
      for (int q4 = 0; q4 < 4; ++q4) {
        f32x4 x = *(const f32x4*)(xr + q4 * 4);
        f32x4 wv;
#pragma unroll
        for (int q = 0; q < 4; ++q) wv[q] = o[q4 * 4 + q] + x[q];
        *(f32x4*)(orow + q4 * 4) = wv;
      }
    }
  }
}

extern "C" void kernel_launch(void* const* d_in, const int* in_sizes, int n_in,
                              void* d_out, int out_size, void* d_ws, size_t ws_size,
                              hipStream_t stream) {
  const float* node_x    = (const float*)d_in[0];
  const float* edge_attr = (const float*)d_in[1];
  const int*   eidx      = (const int*)d_in[2];
  const int N = in_sizes[0] / FD;
  const int E = in_sizes[1] / FD;

  char* ws = (char*)d_ws;
  auto aln = [](size_t x) { return (x + 255) & ~(size_t)255; };
  const size_t wpB   = aln(294912);
  const size_t nxbfB = aln((size_t)N * FD * 2);
  const size_t headB = aln((size_t)N * 4);
  const size_t nxtB  = aln((size_t)E * 4);
  const size_t msgB  = (size_t)E * FD * 2;

  unsigned short* wp = (unsigned short*)ws;
  unsigned short* nxbf = nullptr;
  int* head = nullptr; int* nxt = nullptr;
  unsigned short* msg = nullptr; float* agg = nullptr;
  int use_sort = 0;

  if (ws_size >= wpB + nxbfB + headB + nxtB + msgB) {          // full: bf16 table + sort
    use_sort = 1;
    nxbf = (unsigned short*)(ws + wpB);
    head = (int*)(ws + wpB + nxbfB);
    nxt  = (int*)(ws + wpB + nxbfB + headB);
    msg  = (unsigned short*)(ws + wpB + nxbfB + headB + nxtB);
  } else if (ws_size >= wpB + headB + nxtB + msgB) {           // sort, no bf16 table
    use_sort = 1;
    head = (int*)(ws + wpB);
    nxt  = (int*)(ws + wpB + headB);
    msg  = (unsigned short*)(ws + wpB + headB + nxtB);
  } else {                                                     // atomic fallback
    agg = (float*)(ws + wpB);
  }

  if (use_sort) (void)hipMemsetAsync(head, 0xFF, (size_t)N * 4, stream);
  else          (void)hipMemsetAsync(agg, 0, (size_t)N * FD * sizeof(float), stream);

  pack_weights<<<576, 256, 0, stream>>>(
      (const float*)d_in[3], (const float*)d_in[5], (const float*)d_in[7],
      (const float*)d_in[11], (const float*)d_in[13], (const float*)d_in[15], wp);
  if (nxbf) cvt_bf16<<<(N * FD / 8 + 255) / 256, 256, 0, stream>>>(node_x, nxbf, N * FD / 8);
  in_edge_kernel<<<(E + 127) / 128, 256, 0, stream>>>(
      node_x, nxbf, edge_attr, eidx, wp,
      (const float*)d_in[4], (const float*)d_in[6], (const float*)d_in[8],
      (const float*)d_in[9], (const float*)d_in[10],
      msg, head, nxt, agg, use_sort, E);
  in_node_kernel<<<(N + 63) / 64, 512, 0, stream>>>(
      node_x, nxbf, msg, head, nxt, agg, wp,
      (const float*)d_in[12], (const float*)d_in[14], (const float*)d_in[16],
      (const float*)d_in[17], (const float*)d_in[18], (float*)d_out, use_sort, N);
}

// Round 14
// 240.060 us; speedup vs baseline: 1.7692x; 1.7692x over previous
//
#include <hip/hip_runtime.h>

typedef __attribute__((ext_vector_type(4))) float f32x4;
typedef __attribute__((ext_vector_type(8))) __bf16 bf16x8;

constexpr int FD = 128;   // feature dim D = H = 128

typedef __attribute__((address_space(3))) unsigned int* lds_u32p;
typedef const __attribute__((address_space(1))) unsigned int* gbl_u32p;

__device__ __forceinline__ uint4 pack8(const float* v) {
  union { __bf16 h[8]; uint4 u; } cv;
#pragma unroll
  for (int q = 0; q < 8; ++q) cv.h[q] = (__bf16)v[q];
  return cv.u;
}
__device__ __forceinline__ unsigned int pack2(float a, float b) {
  union { __bf16 h[2]; unsigned int u; } cv;
  cv.h[0] = (__bf16)a; cv.h[1] = (__bf16)b;
  return cv.u;
}

// node_x f32 -> bf16 table (halves random-gather bytes in the edge kernel)
__global__ void cvt_bf16(const float* __restrict__ x, unsigned short* __restrict__ o, int n8) {
  int i = blockIdx.x * 256 + threadIdx.x;
  if (i >= n8) return;
  const float* p = x + (size_t)i * 8;
  float v[8];
#pragma unroll
  for (int q = 0; q < 8; ++q) v[q] = p[q];
  *(uint4*)(o + (size_t)i * 8) = pack8(v);
}

// Pack a (K,128) f32 weight matrix into 16x16x32 MFMA B-fragment order, bf16:
// dst[((nt*KS + ks)*64 + lane)*8 + e] = W[k][n]
__global__ void pack_weights(const float* __restrict__ mw0, const float* __restrict__ mw1,
                             const float* __restrict__ mw2, const float* __restrict__ uw0,
                             const float* __restrict__ uw1, const float* __restrict__ uw2,
                             unsigned short* __restrict__ wp) {
  int tid = blockIdx.x * 256 + threadIdx.x;   // 576*256 == 147456 exactly
  const float* src; int base, K;
  if      (tid < 49152)  { src = mw0; base = 0;      K = 384; }
  else if (tid < 65536)  { src = mw1; base = 49152;  K = 128; }
  else if (tid < 81920)  { src = mw2; base = 65536;  K = 128; }
  else if (tid < 114688) { src = uw0; base = 81920;  K = 256; }
  else if (tid < 131072) { src = uw1; base = 114688; K = 128; }
  else                   { src = uw2; base = 131072; K = 128; }
  int i = tid - base;
  int k = i >> 7, n = i & 127;
  int KS = K >> 5;
  int dst = base + (((n >> 4) * KS + (k >> 5)) * 64 + ((k >> 3) & 3) * 16 + (n & 15)) * 8 + (k & 7);
  union { __bf16 h; unsigned short s; } cv; cv.h = (__bf16)src[i];
  wp[dst] = cv.s;
}

// Fragment-order LDS layout (R7, validated): chunk(ks,m,lane) at shorts offset
// ((ks*4+m)*64 + (lane&15)*4 + (lane>>4))*8, holding A[m*16+ln][ks*32+g16*8..+8].
// Each 1KB group is 64 linear 16B slots -> global_load_lds-compatible: slot L
// holds A[m*16+(L>>2)][ks*32+(L&3)*8], achieved by per-lane GLOBAL address
// permutation with wave-uniform LDS base (guide m173 pattern).

template<bool RELU>
__device__ __forceinline__ void store_frag(unsigned short* sDst, const f32x4* acc, float bias) {
#pragma unroll
  for (int m = 0; m < 4; ++m)
#pragma unroll
    for (int ri = 0; ri < 4; ++ri) {
      float v = acc[m][ri] + bias;
      if (RELU) v = fmaxf(v, 0.f);
      union { __bf16 h; unsigned short s; } cv; cv.h = (__bf16)v;
      sDst[m * 512 + ri * 32] = cv.s;
    }
}

// Edge kernel: 64 edges/block, 512 threads = 8 waves, wave w owns cols w*16..+15.
// x-gather via global_load_lds DMA (4 per wave, zero VGPR residency).
__global__ __launch_bounds__(512, 6)
void in_edge_kernel(const float* __restrict__ node_x, const unsigned short* __restrict__ nxbf,
                    const float* __restrict__ edge_attr,
                    const int* __restrict__ eidx, const unsigned short* __restrict__ wp,
                    const float* __restrict__ b0p, const float* __restrict__ b1p,
                    const float* __restrict__ b2p, const float* __restrict__ gp,
                    const float* __restrict__ bep,
                    unsigned short* __restrict__ msg, int* __restrict__ head,
                    int* __restrict__ nxt, float* __restrict__ agg,
                    int use_sort, int E) {
  __shared__ unsigned short sBuf[3072 * 8];   // 48KB frag-order buffer
  __shared__ int sSrc[64], sDst[64];
  __shared__ float sG[128], sB[128];

  const int t = threadIdx.x;
  const int e0 = blockIdx.x * 64;
  const int lane = t & 63, w = t >> 6;
  const int ln = lane & 15, g16 = lane >> 4;
  const int rdoff = ln * 32 + g16 * 8;
  const int stoff = (w >> 1) * 2048 + g16 * 128
                  + (((2 * w) + (ln >> 3)) & 3) * 8 + (ln & 7);

  // L0 B pipeline: 6-deep register rotation, initial loads issued before staging
  bf16x8 b0[6];
#pragma unroll
  for (int ks = 0; ks < 6; ++ks)
    b0[ks] = *(const bf16x8*)(wp + (size_t)((w * 12 + ks) * 64 + lane) * 8);
  bf16x8 B1r[4];
#pragma unroll
  for (int ks = 0; ks < 4; ++ks)
    B1r[ks] = *(const bf16x8*)(wp + 49152 + (size_t)((w * 4 + ks) * 64 + lane) * 8);

  if (t < 64) {
    sSrc[t] = (e0 + t < E) ? eidx[e0 + t] : 0;
  } else if (t < 128) {
    int r = t - 64;
    int e = e0 + r;
    int d = (e < E) ? eidx[E + e] : 0;
    sDst[r] = d;
    if (use_sort && e < E) nxt[e] = atomicExch(&head[d], e);   // linked-list build
  } else if (t < 256) {
    sG[t - 128] = gp[t - 128];
  } else if (t < 384) {
    sB[t - 256] = bep[t - 256];
  }
  __syncthreads();

  // ---- stage x tiles ----
  if (nxbf) {
    // 4 global_load_lds per wave: groups g = w*4..w*4+3 over {x_dst,x_src} x 16
#pragma unroll
    for (int i = 0; i < 4; ++i) {
      int g = w * 4 + i;                       // 0..31
      int tile = g >> 4;                       // 0: x_dst, 1: x_src
      int ks = (g >> 2) & 3, m = g & 3;
      int row = m * 16 + (lane >> 2);
      int idx = tile ? sSrc[row] : sDst[row];
      const unsigned short* gp2 = nxbf + (size_t)idx * FD + ks * 32 + (lane & 3) * 8;
      lds_u32p lp = (lds_u32p)&sBuf[tile * 8192 + (size_t)(ks * 4 + m) * 512];
      __builtin_amdgcn_global_load_lds((gbl_u32p)gp2, lp, 16, 0, 0);
    }
  } else {
#pragma unroll
    for (int it = 0; it < 16; ++it) {
      const int type = it >> 3;
      int row = ((it & 7) << 3) + w;
      float2 v = {0.f, 0.f};
      if (e0 + row < E) {
        const float* sp = (type == 0) ? node_x + (size_t)sDst[row] * FD
                                      : node_x + (size_t)sSrc[row] * FD;
        v = *(const float2*)(sp + lane * 2);
      }
      int c = (((type * 4 + (lane >> 4)) * 4 + (row >> 4)) * 64
               + (row & 15) * 4 + ((lane >> 2) & 3)) * 8 + (lane & 3) * 2;
      *(unsigned int*)&sBuf[c] = pack2(v.x, v.y);
    }
  }
#pragma unroll
  for (int it = 0; it < 8; ++it) {           // edge_attr -> ks 8..11 (chunks 2048+)
    int row = it * 8 + w;
    float2 v = {0.f, 0.f};
    if (e0 + row < E) v = *(const float2*)(edge_attr + (size_t)(e0 + row) * FD + lane * 2);
    int c = 16384 + (((lane >> 4) * 4 + (row >> 4)) * 64
                     + (row & 15) * 4 + ((lane >> 2) & 3)) * 8 + (lane & 3) * 2;
    *(unsigned int*)&sBuf[c] = pack2(v.x, v.y);
  }
  __syncthreads();

  const int col = w * 16 + ln;
  const float b0v = b0p[col], b1v = b1p[col], b2v = b2p[col];

  f32x4 acc[4];
#pragma unroll
  for (int m = 0; m < 4; ++m) acc[m] = (f32x4){0.f, 0.f, 0.f, 0.f};

  // ---- layer 0: K=384, pipelined B ----
#pragma unroll
  for (int ks = 0; ks < 12; ++ks) {
    bf16x8 bb = b0[ks % 6];
    if (ks + 6 < 12)
      b0[ks % 6] = *(const bf16x8*)(wp + (size_t)((w * 12 + ks + 6) * 64 + lane) * 8);
#pragma unroll
    for (int m = 0; m < 4; ++m) {
      bf16x8 a = *(const bf16x8*)&sBuf[(ks * 4 + m) * 512 + rdoff];
      acc[m] = __builtin_amdgcn_mfma_f32_16x16x32_bf16(a, bb, acc[m], 0, 0, 0);
    }
  }
  // issue B2 loads now (hidden under C0 store + barrier + L1)
  bf16x8 B2r[4];
#pragma unroll
  for (int ks = 0; ks < 4; ++ks)
    B2r[ks] = *(const bf16x8*)(wp + 65536 + (size_t)((w * 4 + ks) * 64 + lane) * 8);

  __syncthreads();                                  // all L0 A-reads done
  store_frag<true>(sBuf + stoff, acc, b0v);         // C0 -> chunks 0..1023
  __syncthreads();

  // ---- layer 1 ----
#pragma unroll
  for (int m = 0; m < 4; ++m) acc[m] = (f32x4){0.f, 0.f, 0.f, 0.f};
#pragma unroll
  for (int ks = 0; ks < 4; ++ks)
#pragma unroll
    for (int m = 0; m < 4; ++m) {
      bf16x8 a = *(const bf16x8*)&sBuf[(ks * 4 + m) * 512 + rdoff];
      acc[m] = __builtin_amdgcn_mfma_f32_16x16x32_bf16(a, B1r[ks], acc[m], 0, 0, 0);
    }
  store_frag<true>(sBuf + 8192 + stoff, acc, b1v);  // C1 -> chunks 1024..2047 (x_src dead)
  __syncthreads();

  // ---- layer 2 ----
#pragma unroll
  for (int m = 0; m < 4; ++m) acc[m] = (f32x4){0.f, 0.f, 0.f, 0.f};
#pragma unroll
  for (int ks = 0; ks < 4; ++ks)
#pragma unroll
    for (int m = 0; m < 4; ++m) {
      bf16x8 a = *(const bf16x8*)&sBuf[8192 + (ks * 4 + m) * 512 + rdoff];
      acc[m] = __builtin_amdgcn_mfma_f32_16x16x32_bf16(a, B2r[ks], acc[m], 0, 0, 0);
    }
  store_frag<false>(sBuf + stoff, acc, b2v);        // h2 -> chunks 0..1023 (C0 dead)
  __syncthreads();

  // ---- fused LN stats + epilogue, row-wise (8 threads per row) ----
  {
    int row = t >> 3, j = t & 7;
    int a0 = (((j >> 1) * 4 + (row >> 4)) * 64 + (row & 15) * 4 + 2 * (j & 1)) * 8;
    bf16x8 v0 = *(const bf16x8*)&sBuf[a0];
    bf16x8 v1 = *(const bf16x8*)&sBuf[a0 + 8];
    float s1 = 0.f, s2 = 0.f;
#pragma unroll
    for (int q = 0; q < 8; ++q) {
      float a = (float)v0[q], b = (float)v1[q];
      s1 += a + b; s2 += a * a + b * b;
    }
#pragma unroll
    for (int m = 1; m < 8; m <<= 1) {
      s1 += __shfl_xor(s1, m, 64);
      s2 += __shfl_xor(s2, m, 64);
    }
    float mean = s1 * (1.f / 128.f);
    float var  = s2 * (1.f / 128.f) - mean * mean;
    float rstd = rsqrtf(fmaxf(var, 0.f) + 1e-5f);

    int e = e0 + row;
    if (e < E) {
      bf16x8 ea0 = *(const bf16x8*)&sBuf[a0 + 16384];
      bf16x8 ea1 = *(const bf16x8*)&sBuf[a0 + 16384 + 8];
      float val[16];
#pragma unroll
      for (int q = 0; q < 8; ++q) {
        val[q]     = ((float)v0[q] - mean) * rstd * sG[j * 16 + q]     + sB[j * 16 + q]     + (float)ea0[q];
        val[8 + q] = ((float)v1[q] - mean) * rstd * sG[j * 16 + 8 + q] + sB[j * 16 + 8 + q] + (float)ea1[q];
      }
      if (use_sort) {
        uint4* dst = (uint4*)(msg + (size_t)e * FD + j * 16);
        dst[0] = pack8(val);
        dst[1] = pack8(val + 8);
      } else {
        float* ap = agg + (size_t)sDst[row] * FD + j * 16;
#pragma unroll
        for (int q = 0; q < 16; ++q) atomicAdd(ap + q, val[q]);
      }
    }
  }
}

// Node kernel: 64 nodes/block (R7 verbatim; node_x tile via global_load_lds).
__global__ __launch_bounds__(512, 8)
void in_node_kernel(const float* __restrict__ node_x, const unsigned short* __restrict__ nxbf,
                    const unsigned short* __restrict__ msg, const int* __restrict__ head,
                    const int* __restrict__ nxt, const float* __restrict__ agg,
                    const unsigned short* __restrict__ wp,
                    const float* __restrict__ b0p, const float* __restrict__ b1p,
                    const float* __restrict__ b2p, const float* __restrict__ gp,
                    const float* __restrict__ bep, float* __restrict__ out,
                    int use_sort, int N) {
  __shared__ unsigned short sBuf[2048 * 8];   // 32KB frag-order buffer
  __shared__ float sG[128], sB[128];

  const int t = threadIdx.x;
  const int r0 = blockIdx.x * 64;
  const int lane = t & 63, w = t >> 6;
  const int ln = lane & 15, g16 = lane >> 4;
  const int col = w * 16 + ln;
  const int rdoff = ln * 32 + g16 * 8;
  const int stoff = (w >> 1) * 2048 + g16 * 128
                  + (((2 * w) + (ln >> 3)) & 3) * 8 + (ln & 7);

  bf16x8 b0[4];
#pragma unroll
  for (int ks = 0; ks < 4; ++ks)
    b0[ks] = *(const bf16x8*)(wp + 81920 + (size_t)((w * 8 + ks) * 64 + lane) * 8);

  if (t < 128)      sG[t] = gp[t];
  else if (t < 256) sB[t - 128] = bep[t - 128];

  if (nxbf) {
    // 2 global_load_lds per wave: groups g = w*2, w*2+1 (16 groups total)
#pragma unroll
    for (int i = 0; i < 2; ++i) {
      int g = w * 2 + i;                       // 0..15
      int ks = g >> 2, m = g & 3;
      int row = m * 16 + (lane >> 2);
      const unsigned short* gp2 = nxbf + (size_t)(r0 + row) * FD + ks * 32 + (lane & 3) * 8;
      lds_u32p lp = (lds_u32p)&sBuf[(size_t)(ks * 4 + m) * 512];
      __builtin_amdgcn_global_load_lds((gbl_u32p)gp2, lp, 16, 0, 0);
    }
  } else {
#pragma unroll
    for (int it = 0; it < 8; ++it) {
      int row = (it << 3) + w;
      int r = r0 + row;
      float2 v = {0.f, 0.f};
      if (r < N) v = *(const float2*)(node_x + (size_t)r * FD + lane * 2);
      int c = (((lane >> 4) * 4 + (row >> 4)) * 64
               + (row & 15) * 4 + ((lane >> 2) & 3)) * 8 + (lane & 3) * 2;
      *(unsigned int*)&sBuf[c] = pack2(v.x, v.y);
    }
  }

  {
    int row = t >> 3, j = t & 7;
    int node = r0 + row;
    float a[16];
#pragma unroll
    for (int q = 0; q < 16; ++q) a[q] = 0.f;
    if (node < N) {
      if (use_sort) {
        int e = head[node];
        while (e >= 0) {
          int ne = nxt[e];
          bf16x8 m0 = *(const bf16x8*)(msg + (size_t)e * FD + j * 16);
          bf16x8 m1 = *(const bf16x8*)(msg + (size_t)e * FD + j * 16 + 8);
#pragma unroll
          for (int q = 0; q < 8; ++q) { a[q] += (float)m0[q]; a[8 + q] += (float)m1[q]; }
          e = ne;
        }
      } else {
        const float* ap = agg + (size_t)node * FD + j * 16;
#pragma unroll
        for (int q4 = 0; q4 < 4; ++q4) {
          f32x4 u = *(const f32x4*)(ap + q4 * 4);
#pragma unroll
          for (int q = 0; q < 4; ++q) a[q4 * 4 + q] = u[q];
        }
      }
    }
    int c = 8192 + (((j >> 1) * 4 + (row >> 4)) * 64 + (row & 15) * 4 + 2 * (j & 1)) * 8;
    *(uint4*)&sBuf[c] = pack8(a);
    *(uint4*)&sBuf[c + 8] = pack8(a + 8);
  }
  __syncthreads();

  const float b0v = b0p[col], b1v = b1p[col], b2v = b2p[col];

  f32x4 acc[4];
#pragma unroll
  for (int m = 0; m < 4; ++m) acc[m] = (f32x4){0.f, 0.f, 0.f, 0.f};

#pragma unroll
  for (int ks = 0; ks < 8; ++ks) {
    bf16x8 bb = b0[ks % 4];
    if (ks + 4 < 8)
      b0[ks % 4] = *(const bf16x8*)(wp + 81920 + (size_t)((w * 8 + ks + 4) * 64 + lane) * 8);
#pragma unroll
    for (int m = 0; m < 4; ++m) {
      bf16x8 a = *(const bf16x8*)&sBuf[(ks * 4 + m) * 512 + rdoff];
      acc[m] = __builtin_amdgcn_mfma_f32_16x16x32_bf16(a, bb, acc[m], 0, 0, 0);
    }
  }
  bf16x8 B1r[4];
#pragma unroll
  for (int ks = 0; ks < 4; ++ks)
    B1r[ks] = *(const bf16x8*)(wp + 114688 + (size_t)((w * 4 + ks) * 64 + lane) * 8);

  __syncthreads();
  store_frag<true>(sBuf + stoff, acc, b0v);
  __syncthreads();

#pragma unroll
  for (int m = 0; m < 4; ++m) acc[m] = (f32x4){0.f, 0.f, 0.f, 0.f};
#pragma unroll
  for (int ks = 0; ks < 4; ++ks)
#pragma unroll
    for (int m = 0; m < 4; ++m) {
      bf16x8 a = *(const bf16x8*)&sBuf[(ks * 4 + m) * 512 + rdoff];
      acc[m] = __builtin_amdgcn_mfma_f32_16x16x32_bf16(a, B1r[ks], acc[m], 0, 0, 0);
    }
  bf16x8 B2r[4];
#pragma unroll
  for (int ks = 0; ks < 4; ++ks)
    B2r[ks] = *(const bf16x8*)(wp + 131072 + (size_t)((w * 4 + ks) * 64 + lane) * 8);
  store_frag<true>(sBuf + 8192 + stoff, acc, b1v);
  __syncthreads();

#pragma unroll
  for (int m = 0; m < 4; ++m) acc[m] = (f32x4){0.f, 0.f, 0.f, 0.f};
#pragma unroll
  for (int ks = 0; ks < 4; ++ks)
#pragma unroll
    for (int m = 0; m < 4; ++m) {
      bf16x8 a = *(const bf16x8*)&sBuf[8192 + (ks * 4 + m) * 512 + rdoff];
      acc[m] = __builtin_amdgcn_mfma_f32_16x16x32_bf16(a, B2r[ks], acc[m], 0, 0, 0);
    }
  store_frag<false>(sBuf + stoff, acc, b2v);
  __syncthreads();

  {
    int row = t >> 3, j = t & 7;
    int a0 = (((j >> 1) * 4 + (row >> 4)) * 64 + (row & 15) * 4 + 2 * (j & 1)) * 8;
    bf16x8 v0 = *(const bf16x8*)&sBuf[a0];
    bf16x8 v1 = *(const bf16x8*)&sBuf[a0 + 8];
    float s1 = 0.f, s2 = 0.f;
#pragma unroll
    for (int q = 0; q < 8; ++q) {
      float a = (float)v0[q], b = (float)v1[q];
      s1 += a + b; s2 += a * a + b * b;
    }
#pragma unroll
    for (int m = 1; m < 8; m <<= 1) {
      s1 += __shfl_xor(s1, m, 64);
      s2 += __shfl_xor(s2, m, 64);
    }
    float mean = s1 * (1.f / 128.f);
    float var  = s2 * (1.f / 128.f) - mean * mean;
    float rstd = rsqrtf(fmaxf(var, 0.f) + 1e-5f);

    int node = r0 + row;
    if (node < N) {
      float o[16];
#pragma unroll
      for (int q = 0; q < 8; ++q) {
        o[q]     = ((float)v0[q] - mean) * rstd * sG[j * 16 + q]     + sB[j * 16 + q];
        o[8 + q] = ((float)v1[q] - mean) * rstd * sG[j * 16 + 8 + q] + sB[j * 16 + 8 + q];
      }
      const float* xr = node_x + (size_t)node * FD + j * 16;
      float* orow = out + (size_t)node * FD + j * 16;
#pragma unroll
      for (int q4 = 0; q4 < 4; ++q4) {
        f32x4 x = *(const f32x4*)(xr + q4 * 4);
        f32x4 wv;
#pragma unroll
        for (int q = 0; q < 4; ++q) wv[q] = o[q4 * 4 + q] + x[q];
        *(f32x4*)(orow + q4 * 4) = wv;
      }
    }
  }
}

extern "C" void kernel_launch(void* const* d_in, const int* in_sizes, int n_in,
                              void* d_out, int out_size, void* d_ws, size_t ws_size,
                              hipStream_t stream) {
  const float* node_x    = (const float*)d_in[0];
  const float* edge_attr = (const float*)d_in[1];
  const int*   eidx      = (const int*)d_in[2];
  const int N = in_sizes[0] / FD;
  const int E = in_sizes[1] / FD;

  char* ws = (char*)d_ws;
  auto aln = [](size_t x) { return (x + 255) & ~(size_t)255; };
  const size_t wpB   = aln(294912);
  const size_t nxbfB = aln((size_t)N * FD * 2 + 16384);   // +pad for tail-block DMA overread
  const size_t headB = aln((size_t)N * 4);
  const size_t nxtB  = aln((size_t)E * 4);
  const size_t msgB  = (size_t)E * FD * 2;

  unsigned short* wp = (unsigned short*)ws;
  unsigned short* nxbf = nullptr;
  int* head = nullptr; int* nxt = nullptr;
  unsigned short* msg = nullptr; float* agg = nullptr;
  int use_sort = 0;

  if (ws_size >= wpB + nxbfB + headB + nxtB + msgB) {          // full: bf16 table + sort
    use_sort = 1;
    nxbf = (unsigned short*)(ws + wpB);
    head = (int*)(ws + wpB + nxbfB);
    nxt  = (int*)(ws + wpB + nxbfB + headB);
    msg  = (unsigned short*)(ws + wpB + nxbfB + headB + nxtB);
  } else if (ws_size >= wpB + headB + nxtB + msgB) {           // sort, no bf16 table
    use_sort = 1;
    head = (int*)(ws + wpB);
    nxt  = (int*)(ws + wpB + headB);
    msg  = (unsigned short*)(ws + wpB + headB + nxtB);
  } else {                                                     // atomic fallback
    agg = (float*)(ws + wpB);
  }

  if (use_sort) (void)hipMemsetAsync(head, 0xFF, (size_t)N * 4, stream);
  else          (void)hipMemsetAsync(agg, 0, (size_t)N * FD * sizeof(float), stream);

  pack_weights<<<576, 256, 0, stream>>>(
      (const float*)d_in[3], (const float*)d_in[5], (const float*)d_in[7],
      (const float*)d_in[11], (const float*)d_in[13], (const float*)d_in[15], wp);
  if (nxbf) cvt_bf16<<<(N * FD / 8 + 255) / 256, 256, 0, stream>>>(node_x, nxbf, N * FD / 8);
  in_edge_kernel<<<(E + 63) / 64, 512, 0, stream>>>(
      node_x, nxbf, edge_attr, eidx, wp,
      (const float*)d_in[4], (const float*)d_in[6], (const float*)d_in[8],
      (const float*)d_in[9], (const float*)d_in[10],
      msg, head, nxt, agg, use_sort, E);
  in_node_kernel<<<(N + 63) / 64, 512, 0, stream>>>(
      node_x, nxbf, msg, head, nxt, agg, wp,
      (const float*)d_in[12], (const float*)d_in[14], (const float*)d_in[16],
      (const float*)d_in[17], (const float*)d_in[18], (float*)d_out, use_sort, N);
}